// Round 6
// baseline (153.283 us; speedup 1.0000x reference)
//
#include <hip/hip_runtime.h>
#include <hip/hip_bf16.h>

#define Bn 8
#define Nn 1024
#define Dn 256
#define Hn 4
#define HOn 64
#define Tn 5
#define WTR 80   // WT rows per head: 64 W^T cols + 10 Wa rows + 6 zero pad
#define EDS 128  // ed_lds row stride (words); stride%32==0 -> bank=c0%32, 2 lanes/bank = free

typedef short bf16x8 __attribute__((ext_vector_type(8)));
typedef float f32x4 __attribute__((ext_vector_type(4)));

__device__ __forceinline__ float b2f(unsigned short u) {
    unsigned x = ((unsigned)u) << 16;
    float f;
    __builtin_memcpy(&f, &x, 4);
    return f;
}
__device__ __forceinline__ unsigned bfr(float f) {
    unsigned u;
    __builtin_memcpy(&u, &f, 4);
    return (u + 0x7FFFu + ((u >> 16) & 1u)) >> 16;
}
__device__ __forceinline__ unsigned short f2b(float f) { return (unsigned short)bfr(f); }

__device__ __forceinline__ float fast_exp2(float x) {
#if __has_builtin(__builtin_amdgcn_exp2f)
    return __builtin_amdgcn_exp2f(x);
#else
    float r;
    asm("v_exp_f32 %0, %1" : "=v"(r) : "v"(x));
    return r;
#endif
}

// ---------- fallback: signal "workspace too small" with out = 100.0 ----------
__global__ __launch_bounds__(256) void k_signal(float* __restrict__ out, int n) {
    int i = blockIdx.x * 256 + threadIdx.x;
    if (i < n) out[i] = 100.0f;
}

// ---------- kernel 0: WT [H][80][D] bf16: rows 0-63 = W^T, 64-73 = W.a_src|W.a_dst, 74-79 = 0
__global__ __launch_bounds__(256) void k_transpose_w(const float* __restrict__ W,
                                                     const float* __restrict__ a_src,
                                                     const float* __restrict__ a_dst,
                                                     unsigned short* __restrict__ WT) {
    __shared__ float tile[64][65];
    int h = blockIdx.x >> 2;
    int d0 = (blockIdx.x & 3) * 64;
    int c0 = threadIdx.x & 63;
    int r0 = threadIdx.x >> 6;  // 0..3
#pragma unroll
    for (int r = 0; r < 16; r++) {
        int d = r * 4 + r0;
        tile[d][c0] = W[((size_t)(h * Dn + d0 + d)) * HOn + c0];  // coalesced over e
    }
    __syncthreads();
#pragma unroll
    for (int r = 0; r < 16; r++) {
        int e = r * 4 + r0;
        WT[((size_t)(h * WTR + e)) * Dn + d0 + c0] = f2b(tile[c0][e]);
    }
    for (int t = r0; t < 2 * Tn; t += 4) {
        const float* av = (t < Tn) ? (a_src + (h * Tn + t) * HOn)
                                   : (a_dst + (h * Tn + t - Tn) * HOn);
        float s = 0.f;
#pragma unroll
        for (int e = 0; e < HOn; e++) s += tile[c0][e] * av[e];
        WT[((size_t)(h * WTR + 64 + t)) * Dn + d0 + c0] = f2b(s);
    }
    for (int rr = 74 + r0; rr < WTR; rr += 4)
        WT[((size_t)(h * WTR + rr)) * Dn + d0 + c0] = 0;
}

// ---------- kernel 1: h^T = W^T x X^T via MFMA + adj u8 packing ----------
// R18: e_src/e_dst stored pre-scaled by log2(e) so k_attn's exp is a bare v_exp_f32.
__global__ __launch_bounds__(256) void k_proj(const float* __restrict__ X,
                                              const unsigned short* __restrict__ WT,
                                              const int* __restrict__ adj,
                                              unsigned short* __restrict__ hT,
                                              float* __restrict__ e_src,
                                              float* __restrict__ e_dst,
                                              unsigned* __restrict__ adjp) {
    int tid = threadIdx.x;
    int w = tid >> 6;
    int lane = tid & 63;
    int quad = lane >> 4;
    int l15 = lane & 15;
    int b = blockIdx.x >> 6;
    int i0 = (blockIdx.x & 63) * 16;
    int h = w;
    int bh = b * Hn + h;

    // pack this block's 16 adj rows to u8 (coalesced int4 loads / u32 stores)
    {
        const int* arow = adj + ((size_t)(b * Nn + i0)) * Nn;
        unsigned* aout = adjp + ((size_t)(b * Nn + i0)) * Nn / 4;
#pragma unroll 4
        for (int k = 0; k < 16; k++) {
            int idx = tid + k * 256;
            int4 v = *(const int4*)(arow + (size_t)idx * 4);
            unsigned pk = (unsigned)(v.x & 0xFF) | ((unsigned)(v.y & 0xFF) << 8) |
                          ((unsigned)(v.z & 0xFF) << 16) | ((unsigned)(v.w & 0xFF) << 24);
            aout[idx] = pk;
        }
    }

    bf16x8 Bx[8];
    const float* xf = X + ((size_t)(b * Nn + i0 + l15)) * Dn + quad * 8;
#pragma unroll
    for (int kc = 0; kc < 8; kc++) {
        union { bf16x8 v; unsigned u[4]; } uu;
        const float4* xp = (const float4*)(xf + kc * 32);
        float4 A0 = xp[0], A1 = xp[1];
        __hip_bfloat162 h0 = __float22bfloat162_rn(make_float2(A0.x, A0.y));
        __hip_bfloat162 h1 = __float22bfloat162_rn(make_float2(A0.z, A0.w));
        __hip_bfloat162 h2 = __float22bfloat162_rn(make_float2(A1.x, A1.y));
        __hip_bfloat162 h3 = __float22bfloat162_rn(make_float2(A1.z, A1.w));
        __builtin_memcpy(&uu.u[0], &h0, 4);
        __builtin_memcpy(&uu.u[1], &h1, 4);
        __builtin_memcpy(&uu.u[2], &h2, 4);
        __builtin_memcpy(&uu.u[3], &h3, 4);
        Bx[kc] = uu.v;
    }

    f32x4 acc[5] = {{0.f, 0.f, 0.f, 0.f}, {0.f, 0.f, 0.f, 0.f}, {0.f, 0.f, 0.f, 0.f},
                    {0.f, 0.f, 0.f, 0.f}, {0.f, 0.f, 0.f, 0.f}};
    const unsigned short* wbase = WT + (size_t)h * WTR * Dn;
#pragma unroll
    for (int kc = 0; kc < 8; kc++) {
#pragma unroll
        for (int et = 0; et < 5; et++) {
            bf16x8 Aw = *(const bf16x8*)(wbase + (size_t)(et * 16 + l15) * Dn + kc * 32 + quad * 8);
            acc[et] = __builtin_amdgcn_mfma_f32_16x16x32_bf16(Aw, Bx[kc], acc[et], 0, 0, 0);
        }
    }

#pragma unroll
    for (int et = 0; et < 4; et++) {
#pragma unroll
        for (int reg = 0; reg < 4; reg++) {
            int e = et * 16 + quad * 4 + reg;
            hT[((size_t)bh * HOn + e) * Nn + i0 + l15] = f2b(acc[et][reg]);
        }
    }
#pragma unroll
    for (int reg = 0; reg < 4; reg++) {
        int t = quad * 4 + reg;
        if (t < Tn)
            e_src[((size_t)bh * Tn + t) * Nn + i0 + l15] = acc[4][reg] * 1.4426950408889634f;
        else if (t < 2 * Tn)
            e_dst[((size_t)bh * Tn + (t - Tn)) * Nn + i0 + l15] = acc[4][reg] * 1.4426950408889634f;
    }
}

// ---------- kernel 2: fused attention — R22: asm-pinned chunk-top hT loads ----------
// grid: B * (N/16) = 512 blocks x 512 threads (8 waves); wave = (head = w&3, j-half = w>>2).
// R21 post-mortem: rotation+setprio bundle REGRESSED (43.0->50.1 despite occupancy up);
// reverted both. R22: the PV-load-latency theory gets its clean test. R19 failed because
// the allocator SANK the C-level prefetch (VGPR stayed 72); asm volatile loads cannot be
// sunk and their "=v" outputs must be materialized. 8 b128 hT loads issued at chunk top,
// 8 more after P1 row 7 (staggers peak pressure; +64 VGPR -> ~120 < 128 cliff, keeps
// 4 waves/SIMD = 2 blocks/CU). One s_waitcnt vmcnt(0) + sched_barrier(0) before PV
// (rule #18: MFMA hoists past bare asm waitcnt without the sched_barrier). No "memory"
// clobber on the loads so the compiler's waitcnt pass doesn't conservatively drain.
// BIND CHECK: VGPR_Count must rise to ~110-125; if it stays ~60-75 the outputs spilled
// and the experiment is void. Kept: full-chunk adj+ed reg prefetch (R20); EDS=128;
// sentinel rows + LDS-gather pass-1 (R18); l via 5th MFMA tile (R13); u8 adj (R16);
// grid/block shape optimum (R17); no min-waves (R7 spill); rolled chunk loop (R8 spill).
__global__ __launch_bounds__(512) void k_attn(const unsigned char* __restrict__ adjp,
                                              const float* __restrict__ e_src,
                                              const float* __restrict__ e_dst,
                                              const unsigned short* __restrict__ hT,
                                              const float* __restrict__ bias,
                                              const float* __restrict__ gamma,
                                              const float* __restrict__ beta,
                                              float* __restrict__ out) {
    __shared__ __align__(16) unsigned short p_lds[8][16][136];  // 34,816 B
    __shared__ float es2[4][16][8];                             // [hh][row][a], a=0 -> 0.0
    __shared__ float l_lds[8][16];
    __shared__ __align__(16) float ed_lds[8][6 * EDS];          // per-wave, row 0 sentinel
    float* macc = (float*)&p_lds[4][0][0];  // [4 hh][16 r][64 e] f32 overlay (16,384 B)

    int tid = threadIdx.x;
    int w = tid >> 6;
    int lane = tid & 63;
    int quad = lane >> 4;
    int l15 = lane & 15;
    int hh = w & 3;
    int half = w >> 2;
    int b = blockIdx.x >> 6;
    int i0 = (blockIdx.x & 63) * 16;
    int bh = b * Hn + hh;
    int J0 = half * 512;

    const unsigned char* adj_base = adjp + ((size_t)(b * Nn + i0)) * Nn + J0;
    const float* edst = e_dst + (size_t)bh * Tn * Nn + J0;
    const unsigned short* hTb = hT + (size_t)bh * HOn * Nn;

    int c0 = 2 * lane;
    float* edw = &ed_lds[w][0];

    f32x4 acc[4] = {{0.f, 0.f, 0.f, 0.f}, {0.f, 0.f, 0.f, 0.f},
                    {0.f, 0.f, 0.f, 0.f}, {0.f, 0.f, 0.f, 0.f}};
    f32x4 accl = {0.f, 0.f, 0.f, 0.f};  // l row-sums via MFMA with B = ones
    bf16x8 ONES;
    {
        short o = (short)0x3F80;  // bf16 1.0
        ONES = (bf16x8){o, o, o, o, o, o, o, o};
    }

    // ed sentinel row (a = 0): exp2(-3e38 * anything-leaky) == 0 -> masked p = 0
    edw[c0] = -3e38f;
    edw[c0 + 1] = -3e38f;

    // prologue: chunk 0's full 16 adj rows + ed into regs
    unsigned adjC[16], adjN[16];
#pragma unroll
    for (int r = 0; r < 16; r++)
        adjC[r] = *(const unsigned short*)(adj_base + (size_t)r * Nn + c0);
    float2 edr[Tn];
#pragma unroll
    for (int t = 0; t < Tn; t++) edr[t] = *(const float2*)(edst + t * Nn + c0);

    // es2[hh][row][a] staging (waves 0-3): slot 0 = 0.0 sentinel, slots 1..5 = e_src
    if (w < 4) {
        const float* esrc = e_src + (size_t)bh * Tn * Nn;
#pragma unroll
        for (int idx = lane; idx < 96; idx += 64) {
            int t = idx >> 4, row = idx & 15;
            es2[w][row][t] = t ? esrc[(t - 1) * Nn + i0 + row] : 0.f;
        }
    }
    __syncthreads();

// pass-1: p = exp2(leakyrelu(es2[row][a] + ed_lds[a][col])), sentinels make masked -> 0.
// es: LDS broadcast (6 distinct banks, conflict-free); ed: EDS=128 gather (2-way, free).
#define P1ROW(ROW, AV)                                                          \
    {                                                                           \
        int a0 = (int)((AV) & 0xFFu);                                           \
        int a1 = (int)((AV) >> 8);                                              \
        float e0 = es2[hh][ROW][a0];                                            \
        float e1 = es2[hh][ROW][a1];                                            \
        float d0 = edw[a0 * EDS + c0];                                          \
        float d1 = edw[a1 * EDS + c0 + 1];                                      \
        float x0 = e0 + d0; x0 = fmaxf(x0, 0.01f * x0);                         \
        float x1 = e1 + d1; x1 = fmaxf(x1, 0.01f * x1);                         \
        float p0 = fast_exp2(x0);                                               \
        float p1 = fast_exp2(x1);                                               \
        __hip_bfloat162 pp = __float22bfloat162_rn(make_float2(p0, p1));        \
        unsigned pu; __builtin_memcpy(&pu, &pp, 4);                             \
        *(unsigned*)(&p_lds[w][ROW][2 * lane]) = pu;                            \
    }

// asm-pinned b128 load: position-fixed (volatile), output must live in VGPRs.
#define GLOAD(DST, PTR) \
    asm volatile("global_load_dwordx4 %0, %1, off" : "=v"(DST) : "v"(PTR))

#pragma unroll 1
    for (int c = 0; c < 4; c++) {
        int jc = c * 128;  // relative to J0
        // R22: issue first half of this chunk's PV B-fragments NOW (asm-pinned).
        bf16x8 Bfr[16];
#pragma unroll
        for (int k = 0; k < 2; k++)
#pragma unroll
            for (int et = 0; et < 4; et++) {
                const unsigned short* p =
                    hTb + (size_t)(et * 16 + l15) * Nn + J0 + jc + k * 32 + quad * 8;
                GLOAD(Bfr[k * 4 + et], p);
            }
        // commit this chunk's ed regs to LDS rows 1..5 (reads edr loaded a full chunk ago)
#pragma unroll
        for (int t = 0; t < Tn; t++) {
            int wi = (t + 1) * EDS + c0;
            edw[wi] = edr[t].x;
            edw[wi + 1] = edr[t].y;
        }
        // next chunk's FULL adj row set + ed (R20) — consumed next iteration.
        if (c < 3) {
#pragma unroll
            for (int r = 0; r < 16; r++)
                adjN[r] = *(const unsigned short*)(adj_base + (size_t)r * Nn + jc + 128 + c0);
#pragma unroll
            for (int t = 0; t < Tn; t++)
                edr[t] = *(const float2*)(edst + t * Nn + jc + 128 + c0);
        }
        // pass-1 rows 0-7
#pragma unroll
        for (int r = 0; r < 8; r++) P1ROW(r, adjC[r]);
        // second half of PV B-fragments (covered by rows 8-15 + waitcnt position)
#pragma unroll
        for (int k = 2; k < 4; k++)
#pragma unroll
            for (int et = 0; et < 4; et++) {
                const unsigned short* p =
                    hTb + (size_t)(et * 16 + l15) * Nn + J0 + jc + k * 32 + quad * 8;
                GLOAD(Bfr[k * 4 + et], p);
            }
        // pass-1 rows 8-15
#pragma unroll
        for (int r = 8; r < 16; r++) P1ROW(r, adjC[r]);
        // drain asm loads; sched_barrier stops MFMA hoisting above the wait (rule #18)
        asm volatile("s_waitcnt vmcnt(0)" ::: "memory");
        __builtin_amdgcn_sched_barrier(0);
        // PV via MFMA: A = P (own-wave LDS, b128); B from asm-pinned regs; 5th tile = l
#pragma unroll
        for (int k = 0; k < 4; k++) {
            bf16x8 Afr = *(const bf16x8*)(&p_lds[w][l15][k * 32 + quad * 8]);
            accl = __builtin_amdgcn_mfma_f32_16x16x32_bf16(Afr, ONES, accl, 0, 0, 0);
#pragma unroll
            for (int et = 0; et < 4; et++)
                acc[et] = __builtin_amdgcn_mfma_f32_16x16x32_bf16(Afr, Bfr[k * 4 + et],
                                                                  acc[et], 0, 0, 0);
        }
        // promote prefetched adj
        if (c < 3) {
#pragma unroll
            for (int r = 0; r < 16; r++) adjC[r] = adjN[r];
        }
    }
#undef P1ROW
#undef GLOAD

    // l: accl[reg] (any l15 col) = row-sum for row quad*4+reg
    if (l15 == 0) {
#pragma unroll
        for (int reg = 0; reg < 4; reg++) l_lds[w][quad * 4 + reg] = accl[reg];
    }
    __syncthreads();  // all waves done with p_lds (MFMA reads) before macc overlay
    if (w >= 4) {
#pragma unroll
        for (int et = 0; et < 4; et++)
#pragma unroll
            for (int reg = 0; reg < 4; reg++)
                macc[((hh * 16) + quad * 4 + reg) * 64 + et * 16 + l15] = acc[et][reg];
    }
    __syncthreads();
    if (w >= 4) return;

    // merge + epilogue: /l, +bias, relu, +h, LayerNorm over HO, store f32
    float bv[4], gv[4], bev[4];
#pragma unroll
    for (int et = 0; et < 4; et++) {
        int e = et * 16 + l15;
        bv[et] = bias[hh * HOn + e];
        gv[et] = gamma[hh * HOn + e];
        bev[et] = beta[hh * HOn + e];
    }
#pragma unroll
    for (int reg = 0; reg < 4; reg++) {
        int r = quad * 4 + reg;
        int i = i0 + r;
        float lw = l_lds[w][r] + l_lds[w + 4][r];
        float linv = 1.f / fmaxf(lw, 1e-30f);
        float dv[4];
        float s = 0.f, ss = 0.f;
#pragma unroll
        for (int et = 0; et < 4; et++) {
            int e = et * 16 + l15;
            float v = (acc[et][reg] + macc[((hh * 16) + r) * 64 + e]) * linv + bv[et];
            v = (v > 0.f) ? v : 0.f;
            v += b2f(hTb[(size_t)e * Nn + i]);  // residual h
            dv[et] = v;
            s += v;
            ss += v * v;
        }
#pragma unroll
        for (int off = 8; off; off >>= 1) {
            s += __shfl_xor(s, off);
            ss += __shfl_xor(ss, off);
        }
        float mean = s * (1.f / 64.f);
        float var = ss * (1.f / 64.f) - mean * mean;
        float rstd = rsqrtf(var + 1e-6f);
#pragma unroll
        for (int et = 0; et < 4; et++) {
            int e = et * 16 + l15;
            float o = (dv[et] - mean) * rstd * gv[et] + bev[et];
            out[((size_t)(b * Nn + i)) * (Hn * HOn) + hh * HOn + e] = o;
        }
    }
}

extern "C" void kernel_launch(void* const* d_in, const int* in_sizes, int n_in,
                              void* d_out, int out_size, void* d_ws, size_t ws_size,
                              hipStream_t stream) {
    const float* X = (const float*)d_in[0];        // nodes_embed f32 [B,N,D]
    const int* adj = (const int*)d_in[1];          // node_adj int32 [B,N,N]
    const float* W = (const float*)d_in[2];        // [H,D,HO] f32
    const float* a_src = (const float*)d_in[3];    // [H,T,HO] f32
    const float* a_dst = (const float*)d_in[4];    // [H,T,HO] f32
    const float* bias = (const float*)d_in[5];     // [H,HO] f32
    const float* gamma = (const float*)d_in[6];    // [H,HO] f32
    const float* beta = (const float*)d_in[7];     // [H,HO] f32
    float* out = (float*)d_out;                    // [B,N,H*HO] f32

    char* ws = (char*)d_ws;
    size_t off = 0;
    unsigned short* hT = (unsigned short*)(ws + off);  off += (size_t)Bn * Hn * Nn * HOn * 2;  // 4 MB
    unsigned short* WT = (unsigned short*)(ws + off);  off += (size_t)Hn * WTR * Dn * 2;       // 160 KB
    float* e_src = (float*)(ws + off);                 off += (size_t)Bn * Hn * Tn * Nn * 4;   // 640 KB
    float* e_dst = (float*)(ws + off);                 off += (size_t)Bn * Hn * Tn * Nn * 4;   // 640 KB
    unsigned char* adjp = (unsigned char*)(ws + off);  off += (size_t)Bn * Nn * Nn;            // 8 MB

    if (ws_size < off) {
        k_signal<<<(out_size + 255) / 256, 256, 0, stream>>>(out, out_size);
        return;
    }

    k_transpose_w<<<Hn * (Dn / 64), 256, 0, stream>>>(W, a_src, a_dst, WT);
    k_proj<<<Bn * (Nn / 16), 256, 0, stream>>>(X, WT, adj, hT, e_src, e_dst, (unsigned*)adjp);
    k_attn<<<Bn * (Nn / 16), 512, 0, stream>>>(adjp, e_src, e_dst, hT, bias, gamma, beta, out);
}

// Round 7
// 132.089 us; speedup vs baseline: 1.1605x; 1.1605x over previous
//
#include <hip/hip_runtime.h>
#include <hip/hip_bf16.h>

#define Bn 8
#define Nn 1024
#define Dn 256
#define Hn 4
#define HOn 64
#define Tn 5
#define WTR 80   // WT rows per head: 64 W^T cols + 10 Wa rows + 6 zero pad
#define EDS 128  // ed_lds row stride (words); stride%32==0 -> bank=c0%32, 2 lanes/bank = free

typedef short bf16x8 __attribute__((ext_vector_type(8)));
typedef float f32x4 __attribute__((ext_vector_type(4)));

__device__ __forceinline__ float b2f(unsigned short u) {
    unsigned x = ((unsigned)u) << 16;
    float f;
    __builtin_memcpy(&f, &x, 4);
    return f;
}
__device__ __forceinline__ unsigned bfr(float f) {
    unsigned u;
    __builtin_memcpy(&u, &f, 4);
    return (u + 0x7FFFu + ((u >> 16) & 1u)) >> 16;
}
__device__ __forceinline__ unsigned short f2b(float f) { return (unsigned short)bfr(f); }

__device__ __forceinline__ float fast_exp2(float x) {
#if __has_builtin(__builtin_amdgcn_exp2f)
    return __builtin_amdgcn_exp2f(x);
#else
    float r;
    asm("v_exp_f32 %0, %1" : "=v"(r) : "v"(x));
    return r;
#endif
}

// ---------- fallback: signal "workspace too small" with out = 100.0 ----------
__global__ __launch_bounds__(256) void k_signal(float* __restrict__ out, int n) {
    int i = blockIdx.x * 256 + threadIdx.x;
    if (i < n) out[i] = 100.0f;
}

// ---------- kernel 0: WT [H][80][D] bf16: rows 0-63 = W^T, 64-73 = W.a_src|W.a_dst, 74-79 = 0
__global__ __launch_bounds__(256) void k_transpose_w(const float* __restrict__ W,
                                                     const float* __restrict__ a_src,
                                                     const float* __restrict__ a_dst,
                                                     unsigned short* __restrict__ WT) {
    __shared__ float tile[64][65];
    int h = blockIdx.x >> 2;
    int d0 = (blockIdx.x & 3) * 64;
    int c0 = threadIdx.x & 63;
    int r0 = threadIdx.x >> 6;  // 0..3
#pragma unroll
    for (int r = 0; r < 16; r++) {
        int d = r * 4 + r0;
        tile[d][c0] = W[((size_t)(h * Dn + d0 + d)) * HOn + c0];  // coalesced over e
    }
    __syncthreads();
#pragma unroll
    for (int r = 0; r < 16; r++) {
        int e = r * 4 + r0;
        WT[((size_t)(h * WTR + e)) * Dn + d0 + c0] = f2b(tile[c0][e]);
    }
    for (int t = r0; t < 2 * Tn; t += 4) {
        const float* av = (t < Tn) ? (a_src + (h * Tn + t) * HOn)
                                   : (a_dst + (h * Tn + t - Tn) * HOn);
        float s = 0.f;
#pragma unroll
        for (int e = 0; e < HOn; e++) s += tile[c0][e] * av[e];
        WT[((size_t)(h * WTR + 64 + t)) * Dn + d0 + c0] = f2b(s);
    }
    for (int rr = 74 + r0; rr < WTR; rr += 4)
        WT[((size_t)(h * WTR + rr)) * Dn + d0 + c0] = 0;
}

// ---------- kernel 1: h^T = W^T x X^T via MFMA + adj u8 packing + hP fragment-order store --
// R18: e_src/e_dst stored pre-scaled by log2(e) so k_attn's exp is a bare v_exp_f32.
// R23: h stored in MFMA-FRAGMENT ORDER hP[bh][jb=j/16][et=e/16][l15=e%16][q2=(j%16)/8][m=j%8]
// instead of row-major hT[e][j]. Why: k_attn's PV B-loads on hT put 64 lanes on 16 rows
// 2 KB apart = 16 cacheline transactions per instruction (epilogue residual: 64!). That
// address divergence is occupancy-invariant — matches 6 rounds of null scheduling results.
// hP makes every consumer access contiguous. Producer side: per-wave LDS transpose tile
// (bf16 [64][24], 48-B rows: 16-B aligned for b128, banks <=4-way on cheap ops), then
// 2 perfectly-coalesced 1-KB b128 stores replace 16 scattered u16 stores.
__global__ __launch_bounds__(256) void k_proj(const float* __restrict__ X,
                                              const unsigned short* __restrict__ WT,
                                              const int* __restrict__ adj,
                                              unsigned short* __restrict__ hP,
                                              float* __restrict__ e_src,
                                              float* __restrict__ e_dst,
                                              unsigned* __restrict__ adjp) {
    __shared__ unsigned short ptile[4][64][24];  // per-wave transpose tile, 12.3 KB
    int tid = threadIdx.x;
    int w = tid >> 6;
    int lane = tid & 63;
    int quad = lane >> 4;
    int l15 = lane & 15;
    int b = blockIdx.x >> 6;
    int i0 = (blockIdx.x & 63) * 16;
    int h = w;
    int bh = b * Hn + h;

    // pack this block's 16 adj rows to u8 (coalesced int4 loads / u32 stores)
    {
        const int* arow = adj + ((size_t)(b * Nn + i0)) * Nn;
        unsigned* aout = adjp + ((size_t)(b * Nn + i0)) * Nn / 4;
#pragma unroll 4
        for (int k = 0; k < 16; k++) {
            int idx = tid + k * 256;
            int4 v = *(const int4*)(arow + (size_t)idx * 4);
            unsigned pk = (unsigned)(v.x & 0xFF) | ((unsigned)(v.y & 0xFF) << 8) |
                          ((unsigned)(v.z & 0xFF) << 16) | ((unsigned)(v.w & 0xFF) << 24);
            aout[idx] = pk;
        }
    }

    bf16x8 Bx[8];
    const float* xf = X + ((size_t)(b * Nn + i0 + l15)) * Dn + quad * 8;
#pragma unroll
    for (int kc = 0; kc < 8; kc++) {
        union { bf16x8 v; unsigned u[4]; } uu;
        const float4* xp = (const float4*)(xf + kc * 32);
        float4 A0 = xp[0], A1 = xp[1];
        __hip_bfloat162 h0 = __float22bfloat162_rn(make_float2(A0.x, A0.y));
        __hip_bfloat162 h1 = __float22bfloat162_rn(make_float2(A0.z, A0.w));
        __hip_bfloat162 h2 = __float22bfloat162_rn(make_float2(A1.x, A1.y));
        __hip_bfloat162 h3 = __float22bfloat162_rn(make_float2(A1.z, A1.w));
        __builtin_memcpy(&uu.u[0], &h0, 4);
        __builtin_memcpy(&uu.u[1], &h1, 4);
        __builtin_memcpy(&uu.u[2], &h2, 4);
        __builtin_memcpy(&uu.u[3], &h3, 4);
        Bx[kc] = uu.v;
    }

    f32x4 acc[5] = {{0.f, 0.f, 0.f, 0.f}, {0.f, 0.f, 0.f, 0.f}, {0.f, 0.f, 0.f, 0.f},
                    {0.f, 0.f, 0.f, 0.f}, {0.f, 0.f, 0.f, 0.f}};
    const unsigned short* wbase = WT + (size_t)h * WTR * Dn;
#pragma unroll
    for (int kc = 0; kc < 8; kc++) {
#pragma unroll
        for (int et = 0; et < 5; et++) {
            bf16x8 Aw = *(const bf16x8*)(wbase + (size_t)(et * 16 + l15) * Dn + kc * 32 + quad * 8);
            acc[et] = __builtin_amdgcn_mfma_f32_16x16x32_bf16(Aw, Bx[kc], acc[et], 0, 0, 0);
        }
    }

    // h tile -> per-wave LDS (bf16), then 2 coalesced 1-KB fragment-order stores
#pragma unroll
    for (int et = 0; et < 4; et++) {
#pragma unroll
        for (int reg = 0; reg < 4; reg++) {
            int e = et * 16 + quad * 4 + reg;
            ptile[w][e][l15] = f2b(acc[et][reg]);  // ds_write_b16, own-wave tile
        }
    }
    {
        int jb = i0 >> 4;
        int e_lo = lane >> 5;          // 0..1
        int l15v = (lane >> 1) & 15;   // 0..15
        int q2 = lane & 1;             // 0..1
#pragma unroll
        for (int p = 0; p < 2; p++) {
            int et = 2 * p + e_lo;
            bf16x8 v = *(const bf16x8*)(&ptile[w][et * 16 + l15v][q2 * 8]);
            *(bf16x8*)(hP + (((size_t)bh * 64 + jb) * 4 + et) * 256 + l15v * 16 + q2 * 8) = v;
        }
    }
#pragma unroll
    for (int reg = 0; reg < 4; reg++) {
        int t = quad * 4 + reg;
        if (t < Tn)
            e_src[((size_t)bh * Tn + t) * Nn + i0 + l15] = acc[4][reg] * 1.4426950408889634f;
        else if (t < 2 * Tn)
            e_dst[((size_t)bh * Tn + (t - Tn)) * Nn + i0 + l15] = acc[4][reg] * 1.4426950408889634f;
    }
}

// ---------- kernel 2: fused attention — R23: R20 structure + fragment-order hP loads ----
// grid: B * (N/16) = 512 blocks x 512 threads (8 waves); wave = (head = w&3, j-half = w>>2).
// R22 post-mortem: asm-pinned prefetch SPILLED (VGPR 76 vs plan 120, occupancy 19%), yet
// dur ~flat -> occupancy/latency-depth is NOT the limiter. R23 theory: PV B-loads' 16-row
// address divergence (16 line-transactions/inst; epilogue residual: 64) is the invariant
// cost. Fix = hP fragment-order layout: Bf load = 2 contiguous 512-B segments (8 lines,
// optimal); epilogue 8 lines/inst. Structure reverted to R20 (best, 43.0 us): no rotation,
// no setprio (R21 regressed), per-k Bf loads, full-chunk adj+ed reg prefetch.
// Kept: EDS=128 (conflicts benign); sentinel rows + LDS-gather pass-1 (R18); l via 5th
// MFMA tile (R13); u8 adj (R16); grid/block shape optimum (R17); no min-waves (R7 spill).
__global__ __launch_bounds__(512) void k_attn(const unsigned char* __restrict__ adjp,
                                              const float* __restrict__ e_src,
                                              const float* __restrict__ e_dst,
                                              const unsigned short* __restrict__ hP,
                                              const float* __restrict__ bias,
                                              const float* __restrict__ gamma,
                                              const float* __restrict__ beta,
                                              float* __restrict__ out) {
    __shared__ __align__(16) unsigned short p_lds[8][16][136];  // 34,816 B
    __shared__ float es2[4][16][8];                             // [hh][row][a], a=0 -> 0.0
    __shared__ float l_lds[8][16];
    __shared__ __align__(16) float ed_lds[8][6 * EDS];          // per-wave, row 0 sentinel
    float* macc = (float*)&p_lds[4][0][0];  // [4 hh][16 r][64 e] f32 overlay (16,384 B)

    int tid = threadIdx.x;
    int w = tid >> 6;
    int lane = tid & 63;
    int quad = lane >> 4;
    int l15 = lane & 15;
    int hh = w & 3;
    int half = w >> 2;
    int b = blockIdx.x >> 6;
    int i0 = (blockIdx.x & 63) * 16;
    int bh = b * Hn + hh;
    int J0 = half * 512;

    const unsigned char* adj_base = adjp + ((size_t)(b * Nn + i0)) * Nn + J0;
    const float* edst = e_dst + (size_t)bh * Tn * Nn + J0;
    const unsigned short* hPb = hP + (size_t)bh * 64 * 1024;  // [jb][et][l15][q2][m]

    int c0 = 2 * lane;
    float* edw = &ed_lds[w][0];

    f32x4 acc[4] = {{0.f, 0.f, 0.f, 0.f}, {0.f, 0.f, 0.f, 0.f},
                    {0.f, 0.f, 0.f, 0.f}, {0.f, 0.f, 0.f, 0.f}};
    f32x4 accl = {0.f, 0.f, 0.f, 0.f};  // l row-sums via MFMA with B = ones
    bf16x8 ONES;
    {
        short o = (short)0x3F80;  // bf16 1.0
        ONES = (bf16x8){o, o, o, o, o, o, o, o};
    }

    // ed sentinel row (a = 0): exp2(-3e38 * anything-leaky) == 0 -> masked p = 0
    edw[c0] = -3e38f;
    edw[c0 + 1] = -3e38f;

    // prologue: chunk 0's full 16 adj rows + ed into regs
    unsigned adjC[16], adjN[16];
#pragma unroll
    for (int r = 0; r < 16; r++)
        adjC[r] = *(const unsigned short*)(adj_base + (size_t)r * Nn + c0);
    float2 edr[Tn];
#pragma unroll
    for (int t = 0; t < Tn; t++) edr[t] = *(const float2*)(edst + t * Nn + c0);

    // es2[hh][row][a] staging (waves 0-3): slot 0 = 0.0 sentinel, slots 1..5 = e_src
    if (w < 4) {
        const float* esrc = e_src + (size_t)bh * Tn * Nn;
#pragma unroll
        for (int idx = lane; idx < 96; idx += 64) {
            int t = idx >> 4, row = idx & 15;
            es2[w][row][t] = t ? esrc[(t - 1) * Nn + i0 + row] : 0.f;
        }
    }
    __syncthreads();

// pass-1: p = exp2(leakyrelu(es2[row][a] + ed_lds[a][col])), sentinels make masked -> 0.
// es: LDS broadcast (6 distinct banks, conflict-free); ed: EDS=128 gather (2-way, free).
#define P1ROW(ROW, AV)                                                          \
    {                                                                           \
        int a0 = (int)((AV) & 0xFFu);                                           \
        int a1 = (int)((AV) >> 8);                                              \
        float e0 = es2[hh][ROW][a0];                                            \
        float e1 = es2[hh][ROW][a1];                                            \
        float d0 = edw[a0 * EDS + c0];                                          \
        float d1 = edw[a1 * EDS + c0 + 1];                                      \
        float x0 = e0 + d0; x0 = fmaxf(x0, 0.01f * x0);                         \
        float x1 = e1 + d1; x1 = fmaxf(x1, 0.01f * x1);                         \
        float p0 = fast_exp2(x0);                                               \
        float p1 = fast_exp2(x1);                                               \
        __hip_bfloat162 pp = __float22bfloat162_rn(make_float2(p0, p1));        \
        unsigned pu; __builtin_memcpy(&pu, &pp, 4);                             \
        *(unsigned*)(&p_lds[w][ROW][2 * lane]) = pu;                            \
    }

#pragma unroll 1
    for (int c = 0; c < 4; c++) {
        int jc = c * 128;  // relative to J0
        // commit this chunk's ed regs to LDS rows 1..5 (reads edr loaded a full chunk ago)
#pragma unroll
        for (int t = 0; t < Tn; t++) {
            int wi = (t + 1) * EDS + c0;
            edw[wi] = edr[t].x;
            edw[wi + 1] = edr[t].y;
        }
        // next chunk's FULL adj row set + ed (R20) — consumed next iteration,
        // so pass-1 + PV of this chunk (~600+cy) cover the L2/HBM latency.
        if (c < 3) {
#pragma unroll
            for (int r = 0; r < 16; r++)
                adjN[r] = *(const unsigned short*)(adj_base + (size_t)r * Nn + jc + 128 + c0);
#pragma unroll
            for (int t = 0; t < Tn; t++)
                edr[t] = *(const float2*)(edst + t * Nn + jc + 128 + c0);
        }
        // pass-1 over all 16 rows from adjC regs
#pragma unroll
        for (int r = 0; r < 16; r++) P1ROW(r, adjC[r]);
        // PV via MFMA: A = P (own-wave LDS, b128); B = hP fragment-order (coalesced);
        // 5th tile (B=ones) accumulates l row-sums
#pragma unroll
        for (int k = 0; k < 4; k++) {
            bf16x8 Afr = *(const bf16x8*)(&p_lds[w][l15][k * 32 + quad * 8]);
            accl = __builtin_amdgcn_mfma_f32_16x16x32_bf16(Afr, ONES, accl, 0, 0, 0);
            int jb = ((J0 + jc + k * 32) >> 4) + (quad >> 1);
#pragma unroll
            for (int et = 0; et < 4; et++) {
                bf16x8 Bf = *(const bf16x8*)(hPb + ((size_t)jb * 4 + et) * 256 +
                                             l15 * 16 + (quad & 1) * 8);
                acc[et] = __builtin_amdgcn_mfma_f32_16x16x32_bf16(Afr, Bf, acc[et], 0, 0, 0);
            }
        }
        // promote prefetched adj
        if (c < 3) {
#pragma unroll
            for (int r = 0; r < 16; r++) adjC[r] = adjN[r];
        }
    }
#undef P1ROW

    // l: accl[reg] (any l15 col) = row-sum for row quad*4+reg
    if (l15 == 0) {
#pragma unroll
        for (int reg = 0; reg < 4; reg++) l_lds[w][quad * 4 + reg] = accl[reg];
    }
    __syncthreads();  // all waves done with p_lds (MFMA reads) before macc overlay
    if (w >= 4) {
#pragma unroll
        for (int et = 0; et < 4; et++)
#pragma unroll
            for (int reg = 0; reg < 4; reg++)
                macc[((hh * 16) + quad * 4 + reg) * 64 + et * 16 + l15] = acc[et][reg];
    }
    __syncthreads();
    if (w >= 4) return;

    // merge + epilogue: /l, +bias, relu, +h, LayerNorm over HO, store f32
    float bv[4], gv[4], bev[4];
#pragma unroll
    for (int et = 0; et < 4; et++) {
        int e = et * 16 + l15;
        bv[et] = bias[hh * HOn + e];
        gv[et] = gamma[hh * HOn + e];
        bev[et] = beta[hh * HOn + e];
    }
    int jbe = i0 >> 4;
#pragma unroll
    for (int reg = 0; reg < 4; reg++) {
        int r = quad * 4 + reg;
        int i = i0 + r;
        float lw = l_lds[w][r] + l_lds[w + 4][r];
        float linv = 1.f / fmaxf(lw, 1e-30f);
        float dv[4];
        float s = 0.f, ss = 0.f;
        int q2 = r >> 3, m = r & 7;
#pragma unroll
        for (int et = 0; et < 4; et++) {
            int e = et * 16 + l15;
            float v = (acc[et][reg] + macc[((hh * 16) + r) * 64 + e]) * linv + bv[et];
            v = (v > 0.f) ? v : 0.f;
            v += b2f(hPb[((size_t)jbe * 4 + et) * 256 + l15 * 16 + q2 * 8 + m]);  // residual h
            dv[et] = v;
            s += v;
            ss += v * v;
        }
#pragma unroll
        for (int off = 8; off; off >>= 1) {
            s += __shfl_xor(s, off);
            ss += __shfl_xor(ss, off);
        }
        float mean = s * (1.f / 64.f);
        float var = ss * (1.f / 64.f) - mean * mean;
        float rstd = rsqrtf(var + 1e-6f);
#pragma unroll
        for (int et = 0; et < 4; et++) {
            int e = et * 16 + l15;
            float o = (dv[et] - mean) * rstd * gv[et] + bev[et];
            out[((size_t)(b * Nn + i)) * (Hn * HOn) + hh * HOn + e] = o;
        }
    }
}

extern "C" void kernel_launch(void* const* d_in, const int* in_sizes, int n_in,
                              void* d_out, int out_size, void* d_ws, size_t ws_size,
                              hipStream_t stream) {
    const float* X = (const float*)d_in[0];        // nodes_embed f32 [B,N,D]
    const int* adj = (const int*)d_in[1];          // node_adj int32 [B,N,N]
    const float* W = (const float*)d_in[2];        // [H,D,HO] f32
    const float* a_src = (const float*)d_in[3];    // [H,T,HO] f32
    const float* a_dst = (const float*)d_in[4];    // [H,T,HO] f32
    const float* bias = (const float*)d_in[5];     // [H,HO] f32
    const float* gamma = (const float*)d_in[6];    // [H,HO] f32
    const float* beta = (const float*)d_in[7];     // [H,HO] f32
    float* out = (float*)d_out;                    // [B,N,H*HO] f32

    char* ws = (char*)d_ws;
    size_t off = 0;
    unsigned short* hP = (unsigned short*)(ws + off);  off += (size_t)Bn * Hn * Nn * HOn * 2;  // 4 MB
    unsigned short* WT = (unsigned short*)(ws + off);  off += (size_t)Hn * WTR * Dn * 2;       // 160 KB
    float* e_src = (float*)(ws + off);                 off += (size_t)Bn * Hn * Tn * Nn * 4;   // 640 KB
    float* e_dst = (float*)(ws + off);                 off += (size_t)Bn * Hn * Tn * Nn * 4;   // 640 KB
    unsigned char* adjp = (unsigned char*)(ws + off);  off += (size_t)Bn * Nn * Nn;            // 8 MB

    if (ws_size < off) {
        k_signal<<<(out_size + 255) / 256, 256, 0, stream>>>(out, out_size);
        return;
    }

    k_transpose_w<<<Hn * (Dn / 64), 256, 0, stream>>>(W, a_src, a_dst, WT);
    k_proj<<<Bn * (Nn / 16), 256, 0, stream>>>(X, WT, adj, hP, e_src, e_dst, (unsigned*)adjp);
    k_attn<<<Bn * (Nn / 16), 512, 0, stream>>>(adjp, e_src, e_dst, hP, bias, gamma, beta, out);
}

// Round 8
// 122.838 us; speedup vs baseline: 1.2478x; 1.0753x over previous
//
#include <hip/hip_runtime.h>
#include <hip/hip_bf16.h>

#define Bn 8
#define Nn 1024
#define Dn 256
#define Hn 4
#define HOn 64
#define Tn 5
#define WTR 80   // logical WP rows per head: 64 W^T cols + 10 Wa rows + 6 zero pad
#define EDS 128  // ed_lds row stride (words); stride%32==0 -> bank=c0%32, 2 lanes/bank = free

typedef short bf16x8 __attribute__((ext_vector_type(8)));
typedef float f32x4 __attribute__((ext_vector_type(4)));

__device__ __forceinline__ float b2f(unsigned short u) {
    unsigned x = ((unsigned)u) << 16;
    float f;
    __builtin_memcpy(&f, &x, 4);
    return f;
}
__device__ __forceinline__ unsigned bfr(float f) {
    unsigned u;
    __builtin_memcpy(&u, &f, 4);
    return (u + 0x7FFFu + ((u >> 16) & 1u)) >> 16;
}
__device__ __forceinline__ unsigned short f2b(float f) { return (unsigned short)bfr(f); }

__device__ __forceinline__ float fast_exp2(float x) {
#if __has_builtin(__builtin_amdgcn_exp2f)
    return __builtin_amdgcn_exp2f(x);
#else
    float r;
    asm("v_exp_f32 %0, %1" : "=v"(r) : "v"(x));
    return r;
#endif
}

// ---------- fallback: signal "workspace too small" with out = 100.0 ----------
__global__ __launch_bounds__(256) void k_signal(float* __restrict__ out, int n) {
    int i = blockIdx.x * 256 + threadIdx.x;
    if (i < n) out[i] = 100.0f;
}

// ---------- kernel 0: WP in MFMA-FRAGMENT ORDER ----------
// R24: WP[h][kc=0..7][et=0..4][lane=quad*16+l15][m=0..7] (bf16) replaces row-major
// WT[h][row][d]. Consumer (k_proj) A-fragment loads become lane-contiguous 16 B
// (1 KB/wave-inst, coalesced optimum) instead of 16 scattered rows 512 B apart.
// Producer: stage W^T tile + a-row dots in LDS, then write fragment-order coalesced.
__global__ __launch_bounds__(256) void k_transpose_w(const float* __restrict__ W,
                                                     const float* __restrict__ a_src,
                                                     const float* __restrict__ a_dst,
                                                     unsigned short* __restrict__ WP) {
    __shared__ float tile[64][65];    // [d_local][e]
    __shared__ float arow_s[10][64];  // [t][d_local]
    int h = blockIdx.x >> 2;
    int d0 = (blockIdx.x & 3) * 64;
    int c0 = threadIdx.x & 63;
    int r0 = threadIdx.x >> 6;  // 0..3
#pragma unroll
    for (int r = 0; r < 16; r++) {
        int d = r * 4 + r0;
        tile[d][c0] = W[((size_t)(h * Dn + d0 + d)) * HOn + c0];  // coalesced over e
    }
    __syncthreads();
    // a-row dots: arow_s[t][d_local] = sum_e W^T[d][e] * a[t][e]
    for (int t = r0; t < 2 * Tn; t += 4) {
        const float* av = (t < Tn) ? (a_src + (h * Tn + t) * HOn)
                                   : (a_dst + (h * Tn + t - Tn) * HOn);
        float s = 0.f;
#pragma unroll
        for (int e = 0; e < HOn; e++) s += tile[c0][e] * av[e];
        arow_s[t][c0] = s;
    }
    __syncthreads();
    // fragment-order writes: this block covers kc in {kcb, kcb+1}
    int kcb = d0 >> 5;
#pragma unroll
    for (int it = 0; it < 3; it++) {
        int idx = threadIdx.x + it * 256;
        if (idx < 640) {  // 2 kc' x 5 et x 64 lanes
            int kcp = idx / 320;
            int rem = idx % 320;
            int et = rem >> 6;
            int ln = rem & 63;
            int quad = ln >> 4, l15 = ln & 15;
            int dl = kcp * 32 + quad * 8;
            int row = et * 16 + l15;
            union { bf16x8 v; unsigned short u[8]; } ov;
#pragma unroll
            for (int m = 0; m < 8; m++) {
                float x = (row < 64) ? tile[dl + m][row]
                                     : ((row < 74) ? arow_s[row - 64][dl + m] : 0.f);
                ov.u[m] = f2b(x);
            }
            *(bf16x8*)(WP + ((((size_t)h * 8 + kcb + kcp) * 5 + et) * 64 + ln) * 8) = ov.v;
        }
    }
}

// ---------- kernel 1: h^P = W^T x X^T via MFMA + adj u8 packing + hP fragment store ----
// R24: (1) X tile (16 KB) staged ONCE into LDS bf16 by all 256 threads (coalesced 4 KB/
// inst) — removes both the 16-scattered-line divergence AND the 4x per-wave redundancy
// of the old per-wave X loads. (2) A-fragments from WP fragment-order (lane-contiguous).
// R23 kept: hP fragment-order output via ptile. R18 kept: e_src/e_dst pre-scaled log2e.
__global__ __launch_bounds__(256) void k_proj(const float* __restrict__ X,
                                              const unsigned short* __restrict__ WP,
                                              const int* __restrict__ adj,
                                              unsigned short* __restrict__ hP,
                                              float* __restrict__ e_src,
                                              float* __restrict__ e_dst,
                                              unsigned* __restrict__ adjp) {
    __shared__ unsigned short xs[16][264];       // X tile bf16, row pad 8 (16-B aligned rows)
    __shared__ unsigned short ptile[4][64][24];  // per-wave transpose tile
    int tid = threadIdx.x;
    int w = tid >> 6;
    int lane = tid & 63;
    int quad = lane >> 4;
    int l15 = lane & 15;
    int b = blockIdx.x >> 6;
    int i0 = (blockIdx.x & 63) * 16;
    int h = w;
    int bh = b * Hn + h;

    // pack this block's 16 adj rows to u8 (coalesced int4 loads / u32 stores)
    {
        const int* arow = adj + ((size_t)(b * Nn + i0)) * Nn;
        unsigned* aout = adjp + ((size_t)(b * Nn + i0)) * Nn / 4;
#pragma unroll 4
        for (int k = 0; k < 16; k++) {
            int idx = tid + k * 256;
            int4 v = *(const int4*)(arow + (size_t)idx * 4);
            unsigned pk = (unsigned)(v.x & 0xFF) | ((unsigned)(v.y & 0xFF) << 8) |
                          ((unsigned)(v.z & 0xFF) << 16) | ((unsigned)(v.w & 0xFF) << 24);
            aout[idx] = pk;
        }
    }

    // stage X tile: flat f32 index f = it*1024 + tid*4 over [16][256]; float4 per thread
    // per iter — 256 threads x 16 B = 4 KB contiguous per instruction (coalesced optimum).
#pragma unroll
    for (int it = 0; it < 4; it++) {
        int row = it * 4 + (tid >> 6);
        int col = (tid & 63) * 4;
        float4 v = *(const float4*)(X + ((size_t)(b * Nn + i0 + row)) * Dn + col);
        __hip_bfloat162 h0 = __float22bfloat162_rn(make_float2(v.x, v.y));
        __hip_bfloat162 h1 = __float22bfloat162_rn(make_float2(v.z, v.w));
        unsigned u0, u1;
        __builtin_memcpy(&u0, &h0, 4);
        __builtin_memcpy(&u1, &h1, 4);
        unsigned* dst = (unsigned*)&xs[row][col];
        dst[0] = u0;
        dst[1] = u1;
    }
    __syncthreads();

    // B-fragments from LDS (scatter is cheap here)
    bf16x8 Bx[8];
#pragma unroll
    for (int kc = 0; kc < 8; kc++)
        Bx[kc] = *(const bf16x8*)(&xs[l15][kc * 32 + quad * 8]);

    f32x4 acc[5] = {{0.f, 0.f, 0.f, 0.f}, {0.f, 0.f, 0.f, 0.f}, {0.f, 0.f, 0.f, 0.f},
                    {0.f, 0.f, 0.f, 0.f}, {0.f, 0.f, 0.f, 0.f}};
    const unsigned short* wbase = WP + (size_t)h * 8 * 5 * 64 * 8;
#pragma unroll
    for (int kc = 0; kc < 8; kc++) {
#pragma unroll
        for (int et = 0; et < 5; et++) {
            bf16x8 Aw = *(const bf16x8*)(wbase + (((size_t)kc * 5 + et) * 64 + lane) * 8);
            acc[et] = __builtin_amdgcn_mfma_f32_16x16x32_bf16(Aw, Bx[kc], acc[et], 0, 0, 0);
        }
    }

    // h tile -> per-wave LDS (bf16), then 2 coalesced 1-KB fragment-order stores (R23)
#pragma unroll
    for (int et = 0; et < 4; et++) {
#pragma unroll
        for (int reg = 0; reg < 4; reg++) {
            int e = et * 16 + quad * 4 + reg;
            ptile[w][e][l15] = f2b(acc[et][reg]);  // ds_write_b16, own-wave tile
        }
    }
    __builtin_amdgcn_s_waitcnt(0);  // ds_writes of own wave complete (lgkm in-order)
    {
        int jb = i0 >> 4;
        int e_lo = lane >> 5;          // 0..1
        int l15v = (lane >> 1) & 15;   // 0..15
        int q2 = lane & 1;             // 0..1
#pragma unroll
        for (int p = 0; p < 2; p++) {
            int et = 2 * p + e_lo;
            bf16x8 v = *(const bf16x8*)(&ptile[w][et * 16 + l15v][q2 * 8]);
            *(bf16x8*)(hP + (((size_t)bh * 64 + jb) * 4 + et) * 256 + l15v * 16 + q2 * 8) = v;
        }
    }
#pragma unroll
    for (int reg = 0; reg < 4; reg++) {
        int t = quad * 4 + reg;
        if (t < Tn)
            e_src[((size_t)bh * Tn + t) * Nn + i0 + l15] = acc[4][reg] * 1.4426950408889634f;
        else if (t < 2 * Tn)
            e_dst[((size_t)bh * Tn + (t - Tn)) * Nn + i0 + l15] = acc[4][reg] * 1.4426950408889634f;
    }
}

// ---------- kernel 2: fused attention — R23 structure UNCHANGED (measured best) ----------
// grid: B * (N/16) = 512 blocks x 512 threads (8 waves); wave = (head = w&3, j-half = w>>2).
// R23: hP fragment-order PV B-loads (2 contiguous 512-B segments/inst) + R20 full-chunk
// adj+ed reg prefetch. No rotation/setprio (R21 regressed); no reg Bf prefetch (R19/R22
// allocator-refused). EDS=128; sentinel rows + LDS-gather pass-1 (R18); l via 5th MFMA
// tile (R13); u8 adj (R16); grid/block shape optimum (R17); no min-waves (R7 spill).
__global__ __launch_bounds__(512) void k_attn(const unsigned char* __restrict__ adjp,
                                              const float* __restrict__ e_src,
                                              const float* __restrict__ e_dst,
                                              const unsigned short* __restrict__ hP,
                                              const float* __restrict__ bias,
                                              const float* __restrict__ gamma,
                                              const float* __restrict__ beta,
                                              float* __restrict__ out) {
    __shared__ __align__(16) unsigned short p_lds[8][16][136];  // 34,816 B
    __shared__ float es2[4][16][8];                             // [hh][row][a], a=0 -> 0.0
    __shared__ float l_lds[8][16];
    __shared__ __align__(16) float ed_lds[8][6 * EDS];          // per-wave, row 0 sentinel
    float* macc = (float*)&p_lds[4][0][0];  // [4 hh][16 r][64 e] f32 overlay (16,384 B)

    int tid = threadIdx.x;
    int w = tid >> 6;
    int lane = tid & 63;
    int quad = lane >> 4;
    int l15 = lane & 15;
    int hh = w & 3;
    int half = w >> 2;
    int b = blockIdx.x >> 6;
    int i0 = (blockIdx.x & 63) * 16;
    int bh = b * Hn + hh;
    int J0 = half * 512;

    const unsigned char* adj_base = adjp + ((size_t)(b * Nn + i0)) * Nn + J0;
    const float* edst = e_dst + (size_t)bh * Tn * Nn + J0;
    const unsigned short* hPb = hP + (size_t)bh * 64 * 1024;  // [jb][et][l15][q2][m]

    int c0 = 2 * lane;
    float* edw = &ed_lds[w][0];

    f32x4 acc[4] = {{0.f, 0.f, 0.f, 0.f}, {0.f, 0.f, 0.f, 0.f},
                    {0.f, 0.f, 0.f, 0.f}, {0.f, 0.f, 0.f, 0.f}};
    f32x4 accl = {0.f, 0.f, 0.f, 0.f};  // l row-sums via MFMA with B = ones
    bf16x8 ONES;
    {
        short o = (short)0x3F80;  // bf16 1.0
        ONES = (bf16x8){o, o, o, o, o, o, o, o};
    }

    // ed sentinel row (a = 0): exp2(-3e38 * anything-leaky) == 0 -> masked p = 0
    edw[c0] = -3e38f;
    edw[c0 + 1] = -3e38f;

    // prologue: chunk 0's full 16 adj rows + ed into regs
    unsigned adjC[16], adjN[16];
#pragma unroll
    for (int r = 0; r < 16; r++)
        adjC[r] = *(const unsigned short*)(adj_base + (size_t)r * Nn + c0);
    float2 edr[Tn];
#pragma unroll
    for (int t = 0; t < Tn; t++) edr[t] = *(const float2*)(edst + t * Nn + c0);

    // es2[hh][row][a] staging (waves 0-3): slot 0 = 0.0 sentinel, slots 1..5 = e_src
    if (w < 4) {
        const float* esrc = e_src + (size_t)bh * Tn * Nn;
#pragma unroll
        for (int idx = lane; idx < 96; idx += 64) {
            int t = idx >> 4, row = idx & 15;
            es2[w][row][t] = t ? esrc[(t - 1) * Nn + i0 + row] : 0.f;
        }
    }
    __syncthreads();

// pass-1: p = exp2(leakyrelu(es2[row][a] + ed_lds[a][col])), sentinels make masked -> 0.
// es: LDS broadcast (6 distinct banks, conflict-free); ed: EDS=128 gather (2-way, free).
#define P1ROW(ROW, AV)                                                          \
    {                                                                           \
        int a0 = (int)((AV) & 0xFFu);                                           \
        int a1 = (int)((AV) >> 8);                                              \
        float e0 = es2[hh][ROW][a0];                                            \
        float e1 = es2[hh][ROW][a1];                                            \
        float d0 = edw[a0 * EDS + c0];                                          \
        float d1 = edw[a1 * EDS + c0 + 1];                                      \
        float x0 = e0 + d0; x0 = fmaxf(x0, 0.01f * x0);                         \
        float x1 = e1 + d1; x1 = fmaxf(x1, 0.01f * x1);                         \
        float p0 = fast_exp2(x0);                                               \
        float p1 = fast_exp2(x1);                                               \
        __hip_bfloat162 pp = __float22bfloat162_rn(make_float2(p0, p1));        \
        unsigned pu; __builtin_memcpy(&pu, &pp, 4);                             \
        *(unsigned*)(&p_lds[w][ROW][2 * lane]) = pu;                            \
    }

#pragma unroll 1
    for (int c = 0; c < 4; c++) {
        int jc = c * 128;  // relative to J0
        // commit this chunk's ed regs to LDS rows 1..5 (reads edr loaded a full chunk ago)
#pragma unroll
        for (int t = 0; t < Tn; t++) {
            int wi = (t + 1) * EDS + c0;
            edw[wi] = edr[t].x;
            edw[wi + 1] = edr[t].y;
        }
        // next chunk's FULL adj row set + ed (R20) — consumed next iteration,
        // so pass-1 + PV of this chunk (~600+cy) cover the L2/HBM latency.
        if (c < 3) {
#pragma unroll
            for (int r = 0; r < 16; r++)
                adjN[r] = *(const unsigned short*)(adj_base + (size_t)r * Nn + jc + 128 + c0);
#pragma unroll
            for (int t = 0; t < Tn; t++)
                edr[t] = *(const float2*)(edst + t * Nn + jc + 128 + c0);
        }
        // pass-1 over all 16 rows from adjC regs
#pragma unroll
        for (int r = 0; r < 16; r++) P1ROW(r, adjC[r]);
        // PV via MFMA: A = P (own-wave LDS, b128); B = hP fragment-order (coalesced);
        // 5th tile (B=ones) accumulates l row-sums
#pragma unroll
        for (int k = 0; k < 4; k++) {
            bf16x8 Afr = *(const bf16x8*)(&p_lds[w][l15][k * 32 + quad * 8]);
            accl = __builtin_amdgcn_mfma_f32_16x16x32_bf16(Afr, ONES, accl, 0, 0, 0);
            int jb = ((J0 + jc + k * 32) >> 4) + (quad >> 1);
#pragma unroll
            for (int et = 0; et < 4; et++) {
                bf16x8 Bf = *(const bf16x8*)(hPb + ((size_t)jb * 4 + et) * 256 +
                                             l15 * 16 + (quad & 1) * 8);
                acc[et] = __builtin_amdgcn_mfma_f32_16x16x32_bf16(Afr, Bf, acc[et], 0, 0, 0);
            }
        }
        // promote prefetched adj
        if (c < 3) {
#pragma unroll
            for (int r = 0; r < 16; r++) adjC[r] = adjN[r];
        }
    }
#undef P1ROW

    // l: accl[reg] (any l15 col) = row-sum for row quad*4+reg
    if (l15 == 0) {
#pragma unroll
        for (int reg = 0; reg < 4; reg++) l_lds[w][quad * 4 + reg] = accl[reg];
    }
    __syncthreads();  // all waves done with p_lds (MFMA reads) before macc overlay
    if (w >= 4) {
#pragma unroll
        for (int et = 0; et < 4; et++)
#pragma unroll
            for (int reg = 0; reg < 4; reg++)
                macc[((hh * 16) + quad * 4 + reg) * 64 + et * 16 + l15] = acc[et][reg];
    }
    __syncthreads();
    if (w >= 4) return;

    // merge + epilogue: /l, +bias, relu, +h, LayerNorm over HO, store f32
    float bv[4], gv[4], bev[4];
#pragma unroll
    for (int et = 0; et < 4; et++) {
        int e = et * 16 + l15;
        bv[et] = bias[hh * HOn + e];
        gv[et] = gamma[hh * HOn + e];
        bev[et] = beta[hh * HOn + e];
    }
    int jbe = i0 >> 4;
#pragma unroll
    for (int reg = 0; reg < 4; reg++) {
        int r = quad * 4 + reg;
        int i = i0 + r;
        float lw = l_lds[w][r] + l_lds[w + 4][r];
        float linv = 1.f / fmaxf(lw, 1e-30f);
        float dv[4];
        float s = 0.f, ss = 0.f;
        int q2 = r >> 3, m = r & 7;
#pragma unroll
        for (int et = 0; et < 4; et++) {
            int e = et * 16 + l15;
            float v = (acc[et][reg] + macc[((hh * 16) + r) * 64 + e]) * linv + bv[et];
            v = (v > 0.f) ? v : 0.f;
            v += b2f(hPb[((size_t)jbe * 4 + et) * 256 + l15 * 16 + q2 * 8 + m]);  // residual h
            dv[et] = v;
            s += v;
            ss += v * v;
        }
#pragma unroll
        for (int off = 8; off; off >>= 1) {
            s += __shfl_xor(s, off);
            ss += __shfl_xor(ss, off);
        }
        float mean = s * (1.f / 64.f);
        float var = ss * (1.f / 64.f) - mean * mean;
        float rstd = rsqrtf(var + 1e-6f);
#pragma unroll
        for (int et = 0; et < 4; et++) {
            int e = et * 16 + l15;
            float o = (dv[et] - mean) * rstd * gv[et] + bev[et];
            out[((size_t)(b * Nn + i)) * (Hn * HOn) + hh * HOn + e] = o;
        }
    }
}

extern "C" void kernel_launch(void* const* d_in, const int* in_sizes, int n_in,
                              void* d_out, int out_size, void* d_ws, size_t ws_size,
                              hipStream_t stream) {
    const float* X = (const float*)d_in[0];        // nodes_embed f32 [B,N,D]
    const int* adj = (const int*)d_in[1];          // node_adj int32 [B,N,N]
    const float* W = (const float*)d_in[2];        // [H,D,HO] f32
    const float* a_src = (const float*)d_in[3];    // [H,T,HO] f32
    const float* a_dst = (const float*)d_in[4];    // [H,T,HO] f32
    const float* bias = (const float*)d_in[5];     // [H,HO] f32
    const float* gamma = (const float*)d_in[6];    // [H,HO] f32
    const float* beta = (const float*)d_in[7];     // [H,HO] f32
    float* out = (float*)d_out;                    // [B,N,H*HO] f32

    char* ws = (char*)d_ws;
    size_t off = 0;
    unsigned short* hP = (unsigned short*)(ws + off);  off += (size_t)Bn * Hn * Nn * HOn * 2;  // 4 MB
    unsigned short* WP = (unsigned short*)(ws + off);  off += (size_t)Hn * WTR * Dn * 2;       // 160 KB
    float* e_src = (float*)(ws + off);                 off += (size_t)Bn * Hn * Tn * Nn * 4;   // 640 KB
    float* e_dst = (float*)(ws + off);                 off += (size_t)Bn * Hn * Tn * Nn * 4;   // 640 KB
    unsigned char* adjp = (unsigned char*)(ws + off);  off += (size_t)Bn * Nn * Nn;            // 8 MB

    if (ws_size < off) {
        k_signal<<<(out_size + 255) / 256, 256, 0, stream>>>(out, out_size);
        return;
    }

    k_transpose_w<<<Hn * (Dn / 64), 256, 0, stream>>>(W, a_src, a_dst, WP);
    k_proj<<<Bn * (Nn / 16), 256, 0, stream>>>(X, WP, adj, hP, e_src, e_dst, (unsigned*)adjp);
    k_attn<<<Bn * (Nn / 16), 512, 0, stream>>>(adjp, e_src, e_dst, hP, bias, gamma, beta, out);
}